// Round 4
// baseline (442.592 us; speedup 1.0000x reference)
//
#include <hip/hip_runtime.h>

#define DIM_IN 256
#define DIM_H  64
#define SEQ_LEN 512
#define TPB 4   // row-tiles (64 rows each) per prepass block

typedef _Float16 h2_t  __attribute__((ext_vector_type(2)));
typedef _Float16 h8_t  __attribute__((ext_vector_type(8)));
typedef float    f32x4 __attribute__((ext_vector_type(4)));

// addrspace(1) pointers: loads/stores emit global_* (vmcnt-only), never flat_*.
typedef const __attribute__((address_space(1))) unsigned* gcu32_p;
typedef const __attribute__((address_space(1))) _Float16* gch16_p;
typedef const __attribute__((address_space(1))) float*    gcf32_p;
typedef       __attribute__((address_space(1))) float*    gf32_p;

__device__ inline float dot2(h2_t a, h2_t b, float c) {
#if __has_builtin(__builtin_amdgcn_fdot2)
    return __builtin_amdgcn_fdot2(a, b, c, false);
#else
    return c + (float)a[0] * (float)b[0] + (float)a[1] * (float)b[1];
#endif
}
__device__ inline float exp2_(float x) {
#if __has_builtin(__builtin_amdgcn_exp2f)
    return __builtin_amdgcn_exp2f(x);
#else
    return exp2f(x);
#endif
}
__device__ inline float rcp_(float x) {
#if __has_builtin(__builtin_amdgcn_rcpf)
    return __builtin_amdgcn_rcpf(x);
#else
    return __fdividef(1.f, x);
#endif
}

// ---------------------------------------------------------------------------
// Pass 1 (MFMA): x-projections, weights amortized over TPB tiles, X tile
// double-buffered through registers. Outputs pre-scaled for exp2 gates:
//   xur.x = -log2(e)*(xu+bu), xur.y = -log2(e)*(xr+br)   (packed f16x2)
//   xi    =  2*log2(e)*(xi+bi)   (f16 into ws if it fits, else f32 into out)
// Unchanged (prepass time invariant across 4 structural variants so far).
// ---------------------------------------------------------------------------
template <int XI16>
__global__ __launch_bounds__(256, 2)
void gru_prepass_mfma(const float* __restrict__ X,
                      const float* __restrict__ W_input,  const float* __restrict__ b_input,
                      const float* __restrict__ W_update, const float* __restrict__ b_update,
                      const float* __restrict__ W_reset,  const float* __restrict__ b_reset,
                      unsigned* __restrict__ xur_out,
                      _Float16* __restrict__ xi16_out, float* __restrict__ xi32_out)
{
    const int tid  = threadIdx.x;
    const int lane = tid & 63;
    const int wv   = tid >> 6;
    const int q    = lane >> 4;
    const int m16  = lane & 15;

    constexpr int LDK = DIM_IN + 8;
    __shared__ _Float16 xs[64 * LDK];

    const int c = wv * 16 + m16;
    h8_t bu[8], brf[8], bif[8];
#pragma unroll
    for (int kt = 0; kt < 8; ++kt) {
        h8_t u, r, i;
#pragma unroll
        for (int jj = 0; jj < 8; ++jj) {
            const int k = kt * 32 + q * 8 + jj;
            u[jj] = (_Float16)W_update[k * DIM_H + c];
            r[jj] = (_Float16)W_reset [k * DIM_H + c];
            i[jj] = (_Float16)W_input [k * DIM_H + c];
        }
        bu[kt] = u; brf[kt] = r; bif[kt] = i;
    }
    const float bzc = b_update[c], brc = b_reset[c], bic = b_input[c];

    const int tile0 = blockIdx.x * TPB;
    float4 pf[16];
    {
        const float4* xb = (const float4*)(X + (size_t)tile0 * 64 * DIM_IN);
#pragma unroll
        for (int i = 0; i < 16; ++i) pf[i] = xb[tid + 256 * i];
    }

#pragma unroll 1
    for (int tI = 0; tI < TPB; ++tI) {
        // stage current tile to LDS (f32 -> f16)
#pragma unroll
        for (int i = 0; i < 16; ++i) {
            const int f   = tid + 256 * i;
            const int row = f >> 6;
            const int kq  = f & 63;
            const float4 v = pf[i];
            h2_t a, b2;
            a[0]  = (_Float16)v.x; a[1]  = (_Float16)v.y;
            b2[0] = (_Float16)v.z; b2[1] = (_Float16)v.w;
            _Float16* dst = &xs[row * LDK + kq * 4];
            *(h2_t*)dst = a; *(h2_t*)(dst + 2) = b2;
        }
        __syncthreads();
        // prefetch next tile (HBM latency hides under the MFMA phase)
        if (tI + 1 < TPB) {
            const float4* xb = (const float4*)(X + (size_t)(tile0 + tI + 1) * 64 * DIM_IN);
#pragma unroll
            for (int i = 0; i < 16; ++i) pf[i] = xb[tid + 256 * i];
        }
        const size_t orow0 = (size_t)(tile0 + tI) * 64;
#pragma unroll
        for (int rt = 0; rt < 4; ++rt) {
            const int r0 = rt * 16;
            f32x4 au = {0.f,0.f,0.f,0.f}, ar = {0.f,0.f,0.f,0.f}, aa = {0.f,0.f,0.f,0.f};
#pragma unroll
            for (int kt = 0; kt < 8; ++kt) {
                const h8_t a = *(const h8_t*)&xs[(r0 + m16) * LDK + kt * 32 + q * 8];
                au = __builtin_amdgcn_mfma_f32_16x16x32_f16(a, bu[kt],  au, 0, 0, 0);
                ar = __builtin_amdgcn_mfma_f32_16x16x32_f16(a, brf[kt], ar, 0, 0, 0);
                aa = __builtin_amdgcn_mfma_f32_16x16x32_f16(a, bif[kt], aa, 0, 0, 0);
            }
#pragma unroll
            for (int i = 0; i < 4; ++i) {
                const size_t grow = orow0 + r0 + q * 4 + i;
                h2_t pk;
                pk[0] = (_Float16)(-1.44269504f * (au[i] + bzc));
                pk[1] = (_Float16)(-1.44269504f * (ar[i] + brc));
                xur_out[grow * DIM_H + c] = __builtin_bit_cast(unsigned, pk);
                const float xiv = 2.88539008f * (aa[i] + bic);
                if (XI16) xi16_out[grow * DIM_H + c] = (_Float16)xiv;
                else      xi32_out[grow * DIM_H + c] = xiv;
            }
        }
        __syncthreads();
    }
}

// ---------------------------------------------------------------------------
// Pass 2: recurrence. R4: ZERO LDS. The 64-value h broadcast is done in
// registers: per-lane f16 pack + DPP quad_perm [1,0,3,2] (lane j gets lane
// j^1, no wait) + 32 v_readlane of the even lanes -> 32 wave-uniform f16x2
// pairs (SGPRs), consumed directly by v_dot2 as src0. Replaces each ~230-cyc
// LDS write->read roundtrip with ~70 cyc of wait-free VALU/SALU; h-pairs are
// reused free by both the r-dots and z-dots. Ring/addressing = R2-proven.
// ---------------------------------------------------------------------------

// per-lane value v -> 32 wave-uniform packed f16x2 pairs (pair m = lanes 2m,2m+1)
__device__ inline void bcast_pairs(float v, unsigned (&dst)[32]) {
    const unsigned lo = (unsigned)__builtin_bit_cast(unsigned short, (_Float16)v);
    const unsigned nb = (unsigned)__builtin_amdgcn_update_dpp(
        0, (int)lo, 0xB1 /*quad_perm [1,0,3,2]*/, 0xF, 0xF, true);
    const unsigned pair = lo | (nb << 16);   // valid at even lanes
#pragma unroll
    for (int m = 0; m < 32; ++m)
        dst[m] = (unsigned)__builtin_amdgcn_readlane((int)pair, 2 * m);
}

template <int XI16>
__global__
__attribute__((amdgpu_flat_work_group_size(64, 64)))
__attribute__((amdgpu_waves_per_eu(1, 1)))
void gru_rec(const unsigned* __restrict__ xur, const _Float16* __restrict__ xi16,
             const float* xif,
             const float* __restrict__ W_input, const float* __restrict__ W_update,
             const float* __restrict__ W_reset,
             float* __restrict__ out)
{
    const int b = blockIdx.x;
    const int j = threadIdx.x;

    h2_t wu[32], wr[32], wi[32];
#pragma unroll
    for (int m = 0; m < 32; ++m) {
        const int k = DIM_IN + 2 * m;
        h2_t a, cc, d;
        a[0]  = (_Float16)W_update[(k    ) * DIM_H + j];
        a[1]  = (_Float16)W_update[(k + 1) * DIM_H + j];
        cc[0] = (_Float16)W_reset [(k    ) * DIM_H + j];
        cc[1] = (_Float16)W_reset [(k + 1) * DIM_H + j];
        d[0]  = (_Float16)W_input [(k    ) * DIM_H + j];
        d[1]  = (_Float16)W_input [(k + 1) * DIM_H + j];
        wu[m] = a; wr[m] = cc; wi[m] = d;
    }

    float hprev = 0.f;
    unsigned hp[32];            // wave-uniform h pairs (SGPR-resident)
#pragma unroll
    for (int m = 0; m < 32; ++m) hp[m] = 0u;

    // R2-proven addressing: per-lane base, uniform element offset.
    const size_t base = (size_t)b * SEQ_LEN * DIM_H + j;
    gcu32_p xg  = (gcu32_p)(xur  + base);
    gch16_p ig  = (gch16_p)(xi16 + base);
    gcf32_p igf = (gcf32_p)(xif  + base);    // xi source when XI16 == 0
    gf32_p  og  = (gf32_p)(out  + base);

    unsigned ru[8];
    float    rxi[8];
#pragma unroll
    for (int d = 0; d < 8; ++d) {
        ru[d]  = xg[(size_t)d * DIM_H];
        rxi[d] = XI16 ? (float)ig[(size_t)d * DIM_H] : igf[(size_t)d * DIM_H];
    }

#pragma unroll 1
    for (int tb = 0; tb < SEQ_LEN / 8; ++tb) {
#pragma unroll
        for (int u = 0; u < 8; ++u) {
            const int t = tb * 8 + u;
            // consume ring slot (loaded 8 steps ago), refill for t+8
            const h2_t pr = __builtin_bit_cast(h2_t, ru[u]);
            const float xu = (float)pr[0];
            const float xr = (float)pr[1];
            const float xi = rxi[u];
            const int tp = (t + 8 < SEQ_LEN) ? t + 8 : SEQ_LEN - 1;
            ru[u]  = xg[(size_t)tp * DIM_H];
            rxi[u] = XI16 ? (float)ig[(size_t)tp * DIM_H] : igf[(size_t)tp * DIM_H];

            // r- and z-dots straight from the uniform h pairs (no LDS, no wait)
            float arA[8] = {0.f,0.f,0.f,0.f,0.f,0.f,0.f,0.f};
            float azA[4] = {0.f,0.f,0.f,0.f};
#pragma unroll
            for (int m = 0; m < 32; ++m) {
                const h2_t a = __builtin_bit_cast(h2_t, hp[m]);
                arA[m & 7] = dot2(a, wr[m], arA[m & 7]);
                azA[m & 3] = dot2(a, wu[m], azA[m & 3]);
            }
            const float drs = ((arA[0]+arA[4]) + (arA[1]+arA[5]))
                            + ((arA[2]+arA[6]) + (arA[3]+arA[7]));
            const float rg  = rcp_(1.f + exp2_(fmaf(drs, -1.44269504f, xr)));

            // broadcast (h*r) -> uniform pairs for the i-dots
            unsigned sp[32];
            bcast_pairs(hprev * rg, sp);

            const float dzs = (azA[0] + azA[1]) + (azA[2] + azA[3]);
            const float zg  = rcp_(1.f + exp2_(fmaf(dzs, -1.44269504f, xu)));

            float axA[8] = {0.f,0.f,0.f,0.f,0.f,0.f,0.f,0.f};
#pragma unroll
            for (int m = 0; m < 32; ++m) {
                const h2_t a = __builtin_bit_cast(h2_t, sp[m]);
                axA[m & 7] = dot2(a, wi[m], axA[m & 7]);
            }
            const float dxs = ((axA[0]+axA[4]) + (axA[1]+axA[5]))
                            + ((axA[2]+axA[6]) + (axA[3]+axA[7]));
            const float th  = fmaf(-2.f, rcp_(1.f + exp2_(
                                  fmaf(dxs, 2.88539008f, xi))), 1.f);

            const float hn = fmaf(zg, th - hprev, hprev);
            og[(size_t)t * DIM_H] = hn;      // vmcnt-only, fire-and-forget

            // broadcast hn -> next step's uniform h pairs
            bcast_pairs(hn, hp);
            hprev = hn;
        }
    }
}

extern "C" void kernel_launch(void* const* d_in, const int* in_sizes, int n_in,
                              void* d_out, int out_size, void* d_ws, size_t ws_size,
                              hipStream_t stream) {
    const float* inputs   = (const float*)d_in[0];
    const float* W_input  = (const float*)d_in[1];
    const float* b_input  = (const float*)d_in[2];
    const float* W_update = (const float*)d_in[3];
    const float* b_update = (const float*)d_in[4];
    const float* W_reset  = (const float*)d_in[5];
    const float* b_reset  = (const float*)d_in[6];
    float* out = (float*)d_out;

    const int    batch = in_sizes[0] / (SEQ_LEN * DIM_IN);
    const size_t rows  = (size_t)batch * SEQ_LEN;
    const int    nblk  = (int)(rows / 64 / TPB);

    unsigned* xur_w = (unsigned*)d_ws;                       // rows*64*4 B
    _Float16* xi_w  = (_Float16*)(xur_w + rows * DIM_H);     // rows*64*2 B
    const bool xi16 = ws_size >= rows * DIM_H * 6ull;        // 50.3 MB

    if (xi16) {
        gru_prepass_mfma<1><<<nblk, 256, 0, stream>>>(
            inputs, W_input, b_input, W_update, b_update, W_reset, b_reset,
            xur_w, xi_w, out);
        gru_rec<1><<<batch, 64, 0, stream>>>(xur_w, xi_w, out,
                                             W_input, W_update, W_reset, out);
    } else {
        // xi f32 lives in `out`: rec reads slot t+8 before it writes slot t
        gru_prepass_mfma<0><<<nblk, 256, 0, stream>>>(
            inputs, W_input, b_input, W_update, b_update, W_reset, b_reset,
            xur_w, xi_w, out);
        gru_rec<0><<<batch, 64, 0, stream>>>(xur_w, xi_w, out,
                                             W_input, W_update, W_reset, out);
    }
}

// Round 8
// 406.585 us; speedup vs baseline: 1.0886x; 1.0886x over previous
//
#include <hip/hip_runtime.h>

#define DIM_IN 256
#define DIM_H  64
#define SEQ_LEN 512
#define TPB 4   // row-tiles (64 rows each) per prepass block

typedef _Float16 h2_t  __attribute__((ext_vector_type(2)));
typedef _Float16 h8_t  __attribute__((ext_vector_type(8)));
typedef float    f32x4 __attribute__((ext_vector_type(4)));
union H8 { h8_t v; h2_t p[4]; };

// addrspace(1) pointers: loads/stores emit global_* (vmcnt-only), never flat_*.
typedef const __attribute__((address_space(1))) unsigned* gcu32_p;
typedef const __attribute__((address_space(1))) _Float16* gch16_p;
typedef const __attribute__((address_space(1))) float*    gcf32_p;
typedef       __attribute__((address_space(1))) float*    gf32_p;

__device__ inline float dot2(h2_t a, h2_t b, float c) {
#if __has_builtin(__builtin_amdgcn_fdot2)
    return __builtin_amdgcn_fdot2(a, b, c, false);
#else
    return c + (float)a[0] * (float)b[0] + (float)a[1] * (float)b[1];
#endif
}
__device__ inline float exp2_(float x) {
#if __has_builtin(__builtin_amdgcn_exp2f)
    return __builtin_amdgcn_exp2f(x);
#else
    return exp2f(x);
#endif
}
__device__ inline float rcp_(float x) {
#if __has_builtin(__builtin_amdgcn_rcpf)
    return __builtin_amdgcn_rcpf(x);
#else
    return __fdividef(1.f, x);
#endif
}

// Full fence: HW wait + compiler barrier (used once, after ring init).
#define LDS_FENCE()  __asm__ volatile("s_waitcnt lgkmcnt(0)" ::: "memory")
// Compiler-only fence: zero instructions. Ordering between the ds_write and
// the following type-punned ds_reads is provided by (a) this clobber at the
// COMPILER level and (b) the same-wave in-order LDS pipe at the HW level
// (per-wave DS ops are processed in order; lgkmcnt only gates register data
// return, which the compiler tracks per-use). R6's failure deleted BOTH
// barriers; this keeps the compiler one and drops only the HW stall.
#define LDS_CFENCE() __asm__ volatile("" ::: "memory")

// ---------------------------------------------------------------------------
// Pass 1 (MFMA): x-projections, weights amortized over TPB tiles, X tile
// double-buffered through registers. Outputs pre-scaled for exp2 gates:
//   xur.x = -log2(e)*(xu+bu), xur.y = -log2(e)*(xr+br)   (packed f16x2)
//   xi    =  2*log2(e)*(xi+bi)   (f16 into ws if it fits, else f32 into out)
// Byte-exact R2 prepass (422.5us champion).
// ---------------------------------------------------------------------------
template <int XI16>
__global__ __launch_bounds__(256, 2)
void gru_prepass_mfma(const float* __restrict__ X,
                      const float* __restrict__ W_input,  const float* __restrict__ b_input,
                      const float* __restrict__ W_update, const float* __restrict__ b_update,
                      const float* __restrict__ W_reset,  const float* __restrict__ b_reset,
                      unsigned* __restrict__ xur_out,
                      _Float16* __restrict__ xi16_out, float* __restrict__ xi32_out)
{
    const int tid  = threadIdx.x;
    const int lane = tid & 63;
    const int wv   = tid >> 6;
    const int q    = lane >> 4;
    const int m16  = lane & 15;

    constexpr int LDK = DIM_IN + 8;
    __shared__ _Float16 xs[64 * LDK];

    const int c = wv * 16 + m16;
    h8_t bu[8], brf[8], bif[8];
#pragma unroll
    for (int kt = 0; kt < 8; ++kt) {
        h8_t u, r, i;
#pragma unroll
        for (int jj = 0; jj < 8; ++jj) {
            const int k = kt * 32 + q * 8 + jj;
            u[jj] = (_Float16)W_update[k * DIM_H + c];
            r[jj] = (_Float16)W_reset [k * DIM_H + c];
            i[jj] = (_Float16)W_input [k * DIM_H + c];
        }
        bu[kt] = u; brf[kt] = r; bif[kt] = i;
    }
    const float bzc = b_update[c], brc = b_reset[c], bic = b_input[c];

    const int tile0 = blockIdx.x * TPB;
    float4 pf[16];
    {
        const float4* xb = (const float4*)(X + (size_t)tile0 * 64 * DIM_IN);
#pragma unroll
        for (int i = 0; i < 16; ++i) pf[i] = xb[tid + 256 * i];
    }

#pragma unroll 1
    for (int tI = 0; tI < TPB; ++tI) {
        // stage current tile to LDS (f32 -> f16)
#pragma unroll
        for (int i = 0; i < 16; ++i) {
            const int f   = tid + 256 * i;
            const int row = f >> 6;
            const int kq  = f & 63;
            const float4 v = pf[i];
            h2_t a, b2;
            a[0]  = (_Float16)v.x; a[1]  = (_Float16)v.y;
            b2[0] = (_Float16)v.z; b2[1] = (_Float16)v.w;
            _Float16* dst = &xs[row * LDK + kq * 4];
            *(h2_t*)dst = a; *(h2_t*)(dst + 2) = b2;
        }
        __syncthreads();
        // prefetch next tile (HBM latency hides under the MFMA phase)
        if (tI + 1 < TPB) {
            const float4* xb = (const float4*)(X + (size_t)(tile0 + tI + 1) * 64 * DIM_IN);
#pragma unroll
            for (int i = 0; i < 16; ++i) pf[i] = xb[tid + 256 * i];
        }
        const size_t orow0 = (size_t)(tile0 + tI) * 64;
#pragma unroll
        for (int rt = 0; rt < 4; ++rt) {
            const int r0 = rt * 16;
            f32x4 au = {0.f,0.f,0.f,0.f}, ar = {0.f,0.f,0.f,0.f}, aa = {0.f,0.f,0.f,0.f};
#pragma unroll
            for (int kt = 0; kt < 8; ++kt) {
                const h8_t a = *(const h8_t*)&xs[(r0 + m16) * LDK + kt * 32 + q * 8];
                au = __builtin_amdgcn_mfma_f32_16x16x32_f16(a, bu[kt],  au, 0, 0, 0);
                ar = __builtin_amdgcn_mfma_f32_16x16x32_f16(a, brf[kt], ar, 0, 0, 0);
                aa = __builtin_amdgcn_mfma_f32_16x16x32_f16(a, bif[kt], aa, 0, 0, 0);
            }
#pragma unroll
            for (int i = 0; i < 4; ++i) {
                const size_t grow = orow0 + r0 + q * 4 + i;
                h2_t pk;
                pk[0] = (_Float16)(-1.44269504f * (au[i] + bzc));
                pk[1] = (_Float16)(-1.44269504f * (ar[i] + brc));
                xur_out[grow * DIM_H + c] = __builtin_bit_cast(unsigned, pk);
                const float xiv = 2.88539008f * (aa[i] + bic);
                if (XI16) xi16_out[grow * DIM_H + c] = (_Float16)xiv;
                else      xi32_out[grow * DIM_H + c] = xiv;
            }
        }
        __syncthreads();
    }
}

// ---------------------------------------------------------------------------
// Pass 2: recurrence. R8 = byte-exact R2 skeleton (212us proven: per-lane
// stream bases, ring-8, 4-acc dot trees, waves_per_eu(1,1) weight residency,
// r-first phase order) with ONE isolated change: the two in-loop
// s_waitcnt lgkmcnt(0) fences become compiler-only fences (see LDS_CFENCE).
// MODE-2 fused record is ABANDONED (R6/R7: deterministic failure, bit-identical
// absmax with and without fences -> bug lives in that path; not re-rolled).
// ---------------------------------------------------------------------------

#define DOTR(HX, Q)                                                 \
    ar0 = dot2(HX.p[0], wr[4*(Q)+0], ar0);                          \
    ar1 = dot2(HX.p[1], wr[4*(Q)+1], ar1);                          \
    ar2 = dot2(HX.p[2], wr[4*(Q)+2], ar2);                          \
    ar3 = dot2(HX.p[3], wr[4*(Q)+3], ar3);

#define DOTZ(HX, Q)                                                 \
    az0 = dot2(HX.p[0], wu[4*(Q)+0], az0);                          \
    az1 = dot2(HX.p[1], wu[4*(Q)+1], az1);                          \
    az2 = dot2(HX.p[2], wu[4*(Q)+2], az2);                          \
    az3 = dot2(HX.p[3], wu[4*(Q)+3], az3);

#define DOTI(SX, Q)                                                 \
    ax0 = dot2(SX.p[0], wi[4*(Q)+0], ax0);                          \
    ax1 = dot2(SX.p[1], wi[4*(Q)+1], ax1);                          \
    ax2 = dot2(SX.p[2], wi[4*(Q)+2], ax2);                          \
    ax3 = dot2(SX.p[3], wi[4*(Q)+3], ax3);

template <int XI16>
__global__
__attribute__((amdgpu_flat_work_group_size(64, 64)))
__attribute__((amdgpu_waves_per_eu(1, 1)))
void gru_rec(const unsigned* __restrict__ xur, const _Float16* __restrict__ xi16,
             const float* xif,
             const float* __restrict__ W_input, const float* __restrict__ W_update,
             const float* __restrict__ W_reset,
             float* __restrict__ out)
{
    const int b = blockIdx.x;
    const int j = threadIdx.x;

    __shared__ __align__(16) _Float16 hh[DIM_H];
    __shared__ __align__(16) _Float16 ss[DIM_H];

    h2_t wu[32], wr[32], wi[32];
#pragma unroll
    for (int m = 0; m < 32; ++m) {
        const int k = DIM_IN + 2 * m;
        h2_t a, cc, d;
        a[0]  = (_Float16)W_update[(k    ) * DIM_H + j];
        a[1]  = (_Float16)W_update[(k + 1) * DIM_H + j];
        cc[0] = (_Float16)W_reset [(k    ) * DIM_H + j];
        cc[1] = (_Float16)W_reset [(k + 1) * DIM_H + j];
        d[0]  = (_Float16)W_input [(k    ) * DIM_H + j];
        d[1]  = (_Float16)W_input [(k + 1) * DIM_H + j];
        wu[m] = a; wr[m] = cc; wi[m] = d;
    }

    hh[j] = (_Float16)0.f;
    float hprev = 0.f;

    // R2-proven addressing: per-lane base pointers, uniform element offsets.
    const size_t base = (size_t)b * SEQ_LEN * DIM_H + j;
    gcu32_p xg  = (gcu32_p)(xur  + base);
    gch16_p ig  = (gch16_p)(xi16 + base);
    gcf32_p igf = (gcf32_p)(xif  + base);     // xi source when XI16 == 0
    gf32_p  og  = (gf32_p)(out  + base);

    unsigned ru[8];
    float    rxi[8];
#pragma unroll
    for (int d = 0; d < 8; ++d) {
        ru[d]  = xg[(size_t)d * DIM_H];
        rxi[d] = XI16 ? (float)ig[(size_t)d * DIM_H] : igf[(size_t)d * DIM_H];
    }
    LDS_FENCE();   // once, outside the loop (covers hh init) -- exact R2

#pragma unroll 1
    for (int tb = 0; tb < SEQ_LEN / 8; ++tb) {
#pragma unroll
        for (int u = 0; u < 8; ++u) {
            const int t = tb * 8 + u;
            // consume ring slot (loaded 8 steps ago), refill for t+8
            const h2_t pr = __builtin_bit_cast(h2_t, ru[u]);
            const float xu = (float)pr[0];
            const float xr = (float)pr[1];
            const float xi = rxi[u];
            const int tp = (t + 8 < SEQ_LEN) ? t + 8 : SEQ_LEN - 1;
            ru[u]  = xg[(size_t)tp * DIM_H];
            rxi[u] = XI16 ? (float)ig[(size_t)tp * DIM_H] : igf[(size_t)tp * DIM_H];

            // broadcast-read h (8 x b128), keep live for both r and z dots
            const H8* hp = (const H8*)hh;
            H8 hx0 = hp[0], hx1 = hp[1], hx2 = hp[2], hx3 = hp[3],
               hx4 = hp[4], hx5 = hp[5], hx6 = hp[6], hx7 = hp[7];

            // phase A: r-gate -> ss write ASAP
            float ar0 = 0.f, ar1 = 0.f, ar2 = 0.f, ar3 = 0.f;
            DOTR(hx0,0) DOTR(hx1,1) DOTR(hx2,2) DOTR(hx3,3)
            DOTR(hx4,4) DOTR(hx5,5) DOTR(hx6,6) DOTR(hx7,7)
            const float rg = rcp_(1.f + exp2_(
                fmaf((ar0 + ar1) + (ar2 + ar3), -1.44269504f, xr)));
            ss[j] = (_Float16)(hprev * rg);
            LDS_CFENCE();   // compiler ordering only; HW: same-wave DS in-order

            // phase B: issue ss reads, hide their latency under the z dots
            const H8* sp = (const H8*)ss;
            H8 sx0 = sp[0], sx1 = sp[1], sx2 = sp[2], sx3 = sp[3],
               sx4 = sp[4], sx5 = sp[5], sx6 = sp[6], sx7 = sp[7];

            float az0 = 0.f, az1 = 0.f, az2 = 0.f, az3 = 0.f;
            DOTZ(hx0,0) DOTZ(hx1,1) DOTZ(hx2,2) DOTZ(hx3,3)
            DOTZ(hx4,4) DOTZ(hx5,5) DOTZ(hx6,6) DOTZ(hx7,7)
            const float zg = rcp_(1.f + exp2_(
                fmaf((az0 + az1) + (az2 + az3), -1.44269504f, xu)));

            // phase C: candidate
            float ax0 = 0.f, ax1 = 0.f, ax2 = 0.f, ax3 = 0.f;
            DOTI(sx0,0) DOTI(sx1,1) DOTI(sx2,2) DOTI(sx3,3)
            DOTI(sx4,4) DOTI(sx5,5) DOTI(sx6,6) DOTI(sx7,7)
            const float th = fmaf(-2.f, rcp_(1.f + exp2_(
                fmaf((ax0 + ax1) + (ax2 + ax3), 2.88539008f, xi))), 1.f);

            const float hn = fmaf(zg, th - hprev, hprev);
            hh[j] = (_Float16)hn;
            LDS_CFENCE();   // compiler ordering only
            og[(size_t)t * DIM_H] = hn;    // vmcnt-only, fire-and-forget
            hprev = hn;
        }
    }
}

extern "C" void kernel_launch(void* const* d_in, const int* in_sizes, int n_in,
                              void* d_out, int out_size, void* d_ws, size_t ws_size,
                              hipStream_t stream) {
    const float* inputs   = (const float*)d_in[0];
    const float* W_input  = (const float*)d_in[1];
    const float* b_input  = (const float*)d_in[2];
    const float* W_update = (const float*)d_in[3];
    const float* b_update = (const float*)d_in[4];
    const float* W_reset  = (const float*)d_in[5];
    const float* b_reset  = (const float*)d_in[6];
    float* out = (float*)d_out;

    const int    batch = in_sizes[0] / (SEQ_LEN * DIM_IN);
    const size_t rows  = (size_t)batch * SEQ_LEN;
    const int    nblk  = (int)(rows / 64 / TPB);

    unsigned* xur_w = (unsigned*)d_ws;                       // rows*64*4 B
    _Float16* xi_w  = (_Float16*)(xur_w + rows * DIM_H);     // rows*64*2 B
    const bool xi16 = ws_size >= rows * DIM_H * 6ull;        // 50.3 MB (proven)

    if (xi16) {
        gru_prepass_mfma<1><<<nblk, 256, 0, stream>>>(
            inputs, W_input, b_input, W_update, b_update, W_reset, b_reset,
            xur_w, xi_w, out);
        gru_rec<1><<<batch, 64, 0, stream>>>(xur_w, xi_w, out,
                                             W_input, W_update, W_reset, out);
    } else {
        // xi f32 lives in `out`: rec reads slot t+8 before it writes slot t
        gru_prepass_mfma<0><<<nblk, 256, 0, stream>>>(
            inputs, W_input, b_input, W_update, b_update, W_reset, b_reset,
            xur_w, xi_w, out);
        gru_rec<0><<<batch, 64, 0, stream>>>(xur_w, xi_w, out,
                                             W_input, W_update, W_reset, out);
    }
}